// Round 1
// baseline (146.681 us; speedup 1.0000x reference)
//
#include <hip/hip_runtime.h>

#define B_   32
#define C_   16
#define H_   256
#define W_   256
#define HW_  65536      // H_*W_
#define HID_ 128

// ---------------- prep: fold w1 into per-o {A,B,C,b1}, transpose w2 ----------
__global__ __launch_bounds__(128) void nca_prep(
    const float* __restrict__ w1, const float* __restrict__ b1,
    const float* __restrict__ w2,
    float4* __restrict__ coef4, float* __restrict__ w2t)
{
    int o = threadIdx.x;   // 0..127
    float A = 0.f, Bc = 0.f, Cc = 0.f;
    #pragma unroll
    for (int k = 0;  k < 16; ++k) A  += w1[o*48 + k];
    #pragma unroll
    for (int k = 16; k < 32; ++k) Bc += w1[o*48 + k];
    #pragma unroll
    for (int k = 32; k < 48; ++k) Cc += w1[o*48 + k];
    coef4[o] = make_float4(A, Bc, Cc, b1[o]);

    // w2 is [C_][HID_] row-major; write w2t[o][c] so k2 reads 64B contiguous per o
    #pragma unroll
    for (int idx = threadIdx.x; idx < C_*HID_; idx += 128) {
        int c  = idx >> 7;     // idx / 128
        int oo = idx & 127;    // idx % 128
        w2t[oo*C_ + c] = w2[idx];
    }
}

// ---------------- k1: xs[b,p] = sum over 16 channels, float4 vectorized ------
__global__ __launch_bounds__(256) void nca_sum(
    const float* __restrict__ x, float* __restrict__ xs)
{
    int t = blockIdx.x * blockDim.x + threadIdx.x;   // float4 index
    if (t >= B_*HW_/4) return;
    int b  = t >> 14;              // (4t) >> 16
    int p4 = (t << 2) & (HW_-1);   // pixel offset within image
    const float* xp = x + (size_t)b * C_ * HW_ + p4;
    float4 s = make_float4(0.f, 0.f, 0.f, 0.f);
    #pragma unroll
    for (int c = 0; c < C_; ++c) {
        float4 v = *(const float4*)(xp + (size_t)c * HW_);
        s.x += v.x; s.y += v.y; s.z += v.z; s.w += v.w;
    }
    ((float4*)xs)[t] = s;
}

// ---------------- k2: sobel + MLP + stochastic update + alpha flag -----------
__global__ __launch_bounds__(256) void nca_mlp(
    const float* __restrict__ x, const int* __restrict__ mask,
    const float* __restrict__ xs,
    const float4* __restrict__ coef4, const float* __restrict__ w2t,
    const float* __restrict__ b2,
    float* __restrict__ out, unsigned char* __restrict__ alpha)
{
    int t = blockIdx.x * blockDim.x + threadIdx.x;
    if (t >= B_*HW_) return;
    int b = t >> 16;
    int p = t & (HW_-1);
    int i = p >> 8;
    int j = p & (W_-1);

    const float* xsb = xs + (size_t)b * HW_;
    bool im = i > 0, ip = i < H_-1, jm = j > 0, jp = j < W_-1;

    float n11 = xsb[p];
    float n10 = jm ? xsb[p-1]   : 0.f;
    float n12 = jp ? xsb[p+1]   : 0.f;
    float n01 = im ? xsb[p-W_]  : 0.f;
    float n00 = (im && jm) ? xsb[p-W_-1] : 0.f;
    float n02 = (im && jp) ? xsb[p-W_+1] : 0.f;
    float n21 = ip ? xsb[p+W_]  : 0.f;
    float n20 = (ip && jm) ? xsb[p+W_-1] : 0.f;
    float n22 = (ip && jp) ? xsb[p+W_+1] : 0.f;

    // cross-correlation (lax.conv does NOT flip kernels)
    float px = (n02 - n00) + 2.f*(n12 - n10) + (n22 - n20);   // sobel X
    float py = (n20 - n00) + 2.f*(n21 - n01) + (n22 - n02);   // sobel Y
    float s  = n11;                                            // cell id

    float dx[C_];
    #pragma unroll
    for (int c = 0; c < C_; ++c) dx[c] = b2[c];

    for (int o = 0; o < HID_; ++o) {
        float4 cf = coef4[o];   // uniform address -> scalar load
        float h = fmaf(cf.x, px, fmaf(cf.y, py, fmaf(cf.z, s, cf.w)));
        h = fmaxf(h, 0.f);
        #pragma unroll
        for (int c = 0; c < C_; ++c)
            dx[c] = fmaf(w2t[o*C_ + c], h, dx[c]);   // contiguous 64B per o
    }

    float m = (float)mask[t];   // mask is [B,1,H,W]
    size_t base = (size_t)b * C_ * HW_ + p;
    float xn3 = 0.f;
    #pragma unroll
    for (int c = 0; c < C_; ++c) {
        float xn = fmaf(dx[c], m, x[base + (size_t)c * HW_]);
        out[base + (size_t)c * HW_] = xn;
        if (c == 3) xn3 = xn;
    }
    alpha[t] = (xn3 > 0.1f) ? (unsigned char)1 : (unsigned char)0;
}

// ---------------- k3: kill pixels with no alive neighbor ---------------------
__global__ __launch_bounds__(256) void nca_alive(
    const unsigned char* __restrict__ alpha, float* __restrict__ out)
{
    int t = blockIdx.x * blockDim.x + threadIdx.x;
    if (t >= B_*HW_) return;
    int b = t >> 16;
    int p = t & (HW_-1);
    int i = p >> 8;
    int j = p & (W_-1);
    const unsigned char* ab = alpha + (size_t)b * HW_;

    bool im = i > 0, ip = i < H_-1, jm = j > 0, jp = j < W_-1;
    int acc = ab[p];
    acc += jm ? ab[p-1] : 0;
    acc += jp ? ab[p+1] : 0;
    if (im) {
        acc += ab[p-W_];
        acc += jm ? ab[p-W_-1] : 0;
        acc += jp ? ab[p-W_+1] : 0;
    }
    if (ip) {
        acc += ab[p+W_];
        acc += jm ? ab[p+W_-1] : 0;
        acc += jp ? ab[p+W_+1] : 0;
    }
    if (acc == 0) {   // dead: zero all 16 channels (rare with uniform inputs)
        size_t base = (size_t)b * C_ * HW_ + p;
        #pragma unroll
        for (int c = 0; c < C_; ++c) out[base + (size_t)c * HW_] = 0.f;
    }
}

extern "C" void kernel_launch(void* const* d_in, const int* in_sizes, int n_in,
                              void* d_out, int out_size, void* d_ws, size_t ws_size,
                              hipStream_t stream)
{
    const float* x    = (const float*)d_in[0];
    const int*   mask = (const int*)d_in[1];
    const float* w1   = (const float*)d_in[2];
    const float* b1   = (const float*)d_in[3];
    const float* w2   = (const float*)d_in[4];
    const float* b2   = (const float*)d_in[5];
    float* out = (float*)d_out;

    // ws layout: xs (B*HW floats) | alpha (B*HW bytes) | coef4 (128 float4) | w2t (2048 f)
    char* ws = (char*)d_ws;
    float*         xsbuf = (float*)ws;
    unsigned char* alpha = (unsigned char*)(ws + (size_t)B_*HW_*4);
    float4*        coef4 = (float4*)(ws + (size_t)B_*HW_*5);
    float*         w2t   = (float*)(ws + (size_t)B_*HW_*5 + HID_*sizeof(float4));

    nca_prep<<<1, 128, 0, stream>>>(w1, b1, w2, coef4, w2t);

    int n4 = B_*HW_/4;
    nca_sum<<<(n4 + 255)/256, 256, 0, stream>>>(x, xsbuf);

    int n = B_*HW_;
    nca_mlp<<<(n + 255)/256, 256, 0, stream>>>(x, mask, xsbuf, coef4, w2t, b2,
                                               out, alpha);

    nca_alive<<<(n + 255)/256, 256, 0, stream>>>(alpha, out);
}